// Round 1
// baseline (21.070 us; speedup 1.0000x reference)
//
#include <hip/hip_runtime.h>
#include <math.h>

// Problem constants (from reference): B=8, C=16, S=16, L=H*W=1024.
// out[b, o, l] = sum_k x[b, o%16, l+k-511] * wav[o%16, k]   (cross-correlation,
// pad_l=511, pad_r=512). Since C==S==16, output channel o depends only on
// o%16 -> compute 16 distinct convs per batch, broadcast to 16 replicas.

#define L_CONV 1024
#define PAD_L  511

__global__ __launch_bounds__(128)
void wavconv_kernel(const float* __restrict__ x,
                    const float* __restrict__ scales,
                    const float* __restrict__ f_mod,
                    const float* __restrict__ poly_mod,
                    const int*   __restrict__ i_ptr,
                    float* __restrict__ out)
{
    // grid.x = 256: blk = (b*16 + c)*2 + half ; block = 128 threads
    __shared__ float xs[2048];   // zero-padded x row: xs[m+511] = x[m]
    __shared__ float wv[1024];   // wavelet row for this c

    const int tid  = threadIdx.x;
    const int blk  = blockIdx.x;
    const int half = blk & 1;
    const int bc   = blk >> 1;      // b*16 + c
    const int c    = bc & 15;

    // ---- stage x row into LDS with zero padding ----
    const float* xrow = x + ((size_t)bc << 10);
    for (int idx = tid; idx < 2048; idx += 128) {
        const int m = idx - PAD_L;
        float v = 0.0f;
        if (m >= 0 && m < L_CONV) v = xrow[m];
        xs[idx] = v;
    }

    // ---- compute wavelet row for this scale c ----
    const int   ii = i_ptr[0];
    const float fm = f_mod[ii];
    const float p0 = poly_mod[ii * 3 + 0];
    const float p1 = poly_mod[ii * 3 + 1];
    const float p2 = poly_mod[ii * 3 + 2];
    const float sc = scales[c];
    // sigma = f_mod[i] * scale / (2*pi)
    const float sigma = fm * sc * 0.15915494309189535f;

    for (int k = tid; k < L_CONV; k += 128) {
        const float t  = (float)k;
        const float q  = t / sigma;
        const float u  = q * q;
        const float u2 = u * u;
        const float u3 = u2 * u;
        const float poly = 1.0f - p0 * u + p1 * u2 + p2 * u3;
        wv[k] = poly * expf(-0.5f * u);
    }
    __syncthreads();

    // ---- main correlation: each thread computes 4 adjacent outputs ----
    const int l0 = (half << 9) + (tid << 2);   // [half*512, half*512+512)

    float a0 = 0.f, a1 = 0.f, a2 = 0.f, a3 = 0.f;
    float4 xa = *(const float4*)&xs[l0];

    #pragma unroll 8
    for (int k = 0; k < L_CONV; k += 4) {
        const float4 w4 = *(const float4*)&wv[k];          // uniform broadcast
        const float4 xb = *(const float4*)&xs[l0 + k + 4]; // per-lane stride-1

        a0 = fmaf(xa.x, w4.x, a0);
        a0 = fmaf(xa.y, w4.y, a0);
        a0 = fmaf(xa.z, w4.z, a0);
        a0 = fmaf(xa.w, w4.w, a0);

        a1 = fmaf(xa.y, w4.x, a1);
        a1 = fmaf(xa.z, w4.y, a1);
        a1 = fmaf(xa.w, w4.z, a1);
        a1 = fmaf(xb.x, w4.w, a1);

        a2 = fmaf(xa.z, w4.x, a2);
        a2 = fmaf(xa.w, w4.y, a2);
        a2 = fmaf(xb.x, w4.z, a2);
        a2 = fmaf(xb.y, w4.w, a2);

        a3 = fmaf(xa.w, w4.x, a3);
        a3 = fmaf(xb.x, w4.y, a3);
        a3 = fmaf(xb.y, w4.z, a3);
        a3 = fmaf(xb.z, w4.w, a3);

        xa = xb;
    }

    // ---- broadcast to the 16 replicated output channels ----
    const int b = bc >> 4;
    const float4 res = make_float4(a0, a1, a2, a3);
    float* op = out + ((size_t)b << 18) + ((size_t)c << 10) + l0;
    #pragma unroll
    for (int r = 0; r < 16; ++r) {
        *(float4*)op = res;
        op += 16 * 1024;   // next o = c + 16*(r+1)
    }
}

extern "C" void kernel_launch(void* const* d_in, const int* in_sizes, int n_in,
                              void* d_out, int out_size, void* d_ws, size_t ws_size,
                              hipStream_t stream)
{
    const float* x        = (const float*)d_in[0];
    const float* scales   = (const float*)d_in[1];
    const float* f_mod    = (const float*)d_in[2];
    const float* poly_mod = (const float*)d_in[3];
    const int*   i_ptr    = (const int*)d_in[4];
    float* out = (float*)d_out;

    // 8 batches * 16 (b,c) rows ... grid = B*C*2 halves = 256 blocks
    wavconv_kernel<<<256, 128, 0, stream>>>(x, scales, f_mod, poly_mod, i_ptr, out);
}

// Round 2
// 13.503 us; speedup vs baseline: 1.5603x; 1.5603x over previous
//
#include <hip/hip_runtime.h>
#include <math.h>

// out[b, o, l] = sum_k x[b, o%16, l+k-511] * wav[o%16, k], B=8, C=S=16, L=1024.
// 256 output channels = 16 distinct rows broadcast 16x.
//
// Layout: grid 256 = (b*16+c)*2+half, block 256 = 4 waves.
//   wave ks handles K-slice [ks*256, ks*256+256) for all 512 outputs of this half.
//   lane t computes J=8 adjacent outputs l0 = t*8 (rolling 12-float register window).
//   4 partial sums per output recombined through LDS, then broadcast-stored x16.
//
// LDS x/partials are XOR-swizzled (bits[4:2] ^= bits[7:5]) so the 32B-stride
// lane pattern of ds_read/write_b128 covers all 32 banks (else 16-way conflict).

#define SWZ(i) ((i) ^ ((((i) >> 5) & 7) << 2))

__global__ __launch_bounds__(256)
void wavconv_kernel(const float* __restrict__ x,
                    const float* __restrict__ scales,
                    const float* __restrict__ f_mod,
                    const float* __restrict__ poly_mod,
                    const int*   __restrict__ i_ptr,
                    float* __restrict__ out)
{
    __shared__ float xs[1552];    // swizzled zero-padded x segment (+16 overread pad)
    __shared__ float wv[1024];    // wavelet row for this c
    __shared__ float part[2048];  // swizzled [4][512] K-slice partials

    const int tid  = threadIdx.x;
    const int blk  = blockIdx.x;
    const int half = blk & 1;
    const int bc   = blk >> 1;     // b*16 + c
    const int c    = bc & 15;
    const int b    = bc >> 4;

    // ---- stage zero-padded x segment: xs[i] = x[bc][half*512 - 511 + i] ----
    const int xstart = (half << 9) - 511;
    const float* __restrict__ xrow = x + ((size_t)bc << 10);
    for (int i = tid; i < 1536; i += 256) {
        const int m = xstart + i;
        const float v = (m >= 0 && m < 1024) ? xrow[m] : 0.0f;
        xs[SWZ(i)] = v;
    }

    // ---- wavelet row for scale c ----
    const int   ii = i_ptr[0];
    const float fm = f_mod[ii];
    const float p0 = poly_mod[ii * 3 + 0];
    const float p1 = poly_mod[ii * 3 + 1];
    const float p2 = poly_mod[ii * 3 + 2];
    const float sigma = fm * scales[c] * 0.15915494309189535f;  // fm*scale/(2*pi)
    for (int k = tid; k < 1024; k += 256) {
        const float q  = (float)k / sigma;
        const float u  = q * q;
        const float u2 = u * u;
        const float poly = 1.0f - p0 * u + p1 * u2 + p2 * u2 * u;
        wv[k] = poly * expf(-0.5f * u);
    }
    __syncthreads();

    // ---- main correlation: wave ks, lane t -> outputs l0..l0+7, taps k0..k0+255 ----
    const int ks = tid >> 6;
    const int t  = tid & 63;
    const int l0 = t << 3;
    const int k0 = ks << 8;

    float acc[8];
    #pragma unroll
    for (int j = 0; j < 8; ++j) acc[j] = 0.0f;

    float xw[12];
    {
        const int i0 = l0 + k0;
        const float4 xa = *(const float4*)&xs[SWZ(i0)];
        const float4 xb = *(const float4*)&xs[SWZ(i0 + 4)];
        const float4 xc = *(const float4*)&xs[SWZ(i0 + 8)];
        xw[0] = xa.x; xw[1] = xa.y; xw[2]  = xa.z; xw[3]  = xa.w;
        xw[4] = xb.x; xw[5] = xb.y; xw[6]  = xb.z; xw[7]  = xb.w;
        xw[8] = xc.x; xw[9] = xc.y; xw[10] = xc.z; xw[11] = xc.w;
    }

    #pragma unroll 8
    for (int k = k0; k < k0 + 256; k += 4) {
        const float4 w4 = *(const float4*)&wv[k];   // wave-uniform broadcast
        #pragma unroll
        for (int j = 0; j < 8; ++j) {
            acc[j] = fmaf(xw[j + 0], w4.x, acc[j]);
            acc[j] = fmaf(xw[j + 1], w4.y, acc[j]);
            acc[j] = fmaf(xw[j + 2], w4.z, acc[j]);
            acc[j] = fmaf(xw[j + 3], w4.w, acc[j]);
        }
        #pragma unroll
        for (int j = 0; j < 8; ++j) xw[j] = xw[j + 4];
        // next 4 window floats (last iter reads pad region, value unused)
        const float4 xn = *(const float4*)&xs[SWZ(l0 + k + 12)];
        xw[8] = xn.x; xw[9] = xn.y; xw[10] = xn.z; xw[11] = xn.w;
    }

    // ---- combine 4 K-slice partials through LDS ----
    const int pbase = (ks << 9) + l0;
    *(float4*)&part[SWZ(pbase)]     = make_float4(acc[0], acc[1], acc[2], acc[3]);
    *(float4*)&part[SWZ(pbase + 4)] = make_float4(acc[4], acc[5], acc[6], acc[7]);
    __syncthreads();

    const int o = tid << 1;   // 0..510
    float r0 = 0.0f, r1 = 0.0f;
    #pragma unroll
    for (int s = 0; s < 4; ++s) {
        r0 += part[SWZ((s << 9) + o)];
        r1 += part[SWZ((s << 9) + o + 1)];
    }

    // ---- broadcast-store to the 16 replicated output channels ----
    const float2 res = make_float2(r0, r1);
    float* op = out + ((size_t)b << 18) + ((size_t)c << 10) + (half << 9) + o;
    #pragma unroll
    for (int r = 0; r < 16; ++r) {
        *(float2*)op = res;
        op += 1 << 14;   // next replica channel (+16*1024)
    }
}

extern "C" void kernel_launch(void* const* d_in, const int* in_sizes, int n_in,
                              void* d_out, int out_size, void* d_ws, size_t ws_size,
                              hipStream_t stream)
{
    const float* x        = (const float*)d_in[0];
    const float* scales   = (const float*)d_in[1];
    const float* f_mod    = (const float*)d_in[2];
    const float* poly_mod = (const float*)d_in[3];
    const int*   i_ptr    = (const int*)d_in[4];
    float* out = (float*)d_out;

    wavconv_kernel<<<256, 256, 0, stream>>>(x, scales, f_mod, poly_mod, i_ptr, out);
}

// Round 3
// 12.256 us; speedup vs baseline: 1.7191x; 1.1018x over previous
//
#include <hip/hip_runtime.h>
#include <math.h>

// out[b, o, l] = sum_k x[b, o%16, l+k-511] * wav[o%16, k], B=8, C=S=16, L=1024.
// 256 output channels = 16 distinct rows, each broadcast 16x.
//
// Round 3: raise occupancy to 2 waves/SIMD. grid 256 = (b*16+c)*2+half,
// block 512 = 8 waves. Wave ks takes K-slice [ks*128, ks*128+128) over all
// 512 outputs of this half; lane t computes J=8 adjacent outputs (rolling
// 12-float register window -> 16 FMA per ds_read_b128). 8 K-slice partials
// recombined through LDS, then broadcast-stored x16.
//
// LDS x/partials XOR-swizzled (bits[4:2] ^= bits[7:5]): the stride-8-dword
// lane pattern then covers all 32 banks uniformly (8 lanes x 4 dwords per
// 4-bank group = minimum phases, conflict-free).

#define SWZ(i) ((i) ^ ((((i) >> 5) & 7) << 2))

__global__ __launch_bounds__(512)
void wavconv_kernel(const float* __restrict__ x,
                    const float* __restrict__ scales,
                    const float* __restrict__ f_mod,
                    const float* __restrict__ poly_mod,
                    const int*   __restrict__ i_ptr,
                    float* __restrict__ out)
{
    __shared__ float xs[1568];    // swizzled zero-padded x segment (+overread pad)
    __shared__ float wv[1024];    // wavelet row for this c (linear, uniform reads)
    __shared__ float part[4096];  // swizzled [8][512] K-slice partials

    const int tid  = threadIdx.x;
    const int blk  = blockIdx.x;
    const int half = blk & 1;
    const int bc   = blk >> 1;     // b*16 + c
    const int c    = bc & 15;
    const int b    = bc >> 4;

    // ---- stage zero-padded x segment: xs[i] = x[bc][half*512 - 511 + i] ----
    const int xstart = (half << 9) - 511;
    const float* __restrict__ xrow = x + ((size_t)bc << 10);
    for (int i = tid; i < 1536; i += 512) {
        const int m = xstart + i;
        const float v = (m >= 0 && m < 1024) ? xrow[m] : 0.0f;
        xs[SWZ(i)] = v;
    }

    // ---- wavelet row for scale c (2 values/thread) ----
    const int   ii = i_ptr[0];
    const float fm = f_mod[ii];
    const float p0 = poly_mod[ii * 3 + 0];
    const float p1 = poly_mod[ii * 3 + 1];
    const float p2 = poly_mod[ii * 3 + 2];
    const float sigma = fm * scales[c] * 0.15915494309189535f;  // fm*scale/(2*pi)
    for (int k = tid; k < 1024; k += 512) {
        const float q  = (float)k / sigma;
        const float u  = q * q;
        const float u2 = u * u;
        const float poly = 1.0f - p0 * u + p1 * u2 + p2 * u2 * u;
        wv[k] = poly * expf(-0.5f * u);
    }
    __syncthreads();

    // ---- main correlation: wave ks -> taps [ks*128, ks*128+128), lane t -> 8 outputs ----
    const int ks = tid >> 6;       // 0..7
    const int t  = tid & 63;
    const int l0 = t << 3;         // 0..504
    const int k0 = ks << 7;

    float acc[8];
    #pragma unroll
    for (int j = 0; j < 8; ++j) acc[j] = 0.0f;

    float xw[12];
    {
        const int i0 = l0 + k0;
        const float4 xa = *(const float4*)&xs[SWZ(i0)];
        const float4 xb = *(const float4*)&xs[SWZ(i0 + 4)];
        const float4 xc = *(const float4*)&xs[SWZ(i0 + 8)];
        xw[0] = xa.x; xw[1] = xa.y; xw[2]  = xa.z; xw[3]  = xa.w;
        xw[4] = xb.x; xw[5] = xb.y; xw[6]  = xb.z; xw[7]  = xb.w;
        xw[8] = xc.x; xw[9] = xc.y; xw[10] = xc.z; xw[11] = xc.w;
    }

    #pragma unroll 8
    for (int k = k0; k < k0 + 128; k += 4) {
        const float4 w4 = *(const float4*)&wv[k];   // wave-uniform broadcast
        #pragma unroll
        for (int j = 0; j < 8; ++j) {
            acc[j] = fmaf(xw[j + 0], w4.x, acc[j]);
            acc[j] = fmaf(xw[j + 1], w4.y, acc[j]);
            acc[j] = fmaf(xw[j + 2], w4.z, acc[j]);
            acc[j] = fmaf(xw[j + 3], w4.w, acc[j]);
        }
        #pragma unroll
        for (int j = 0; j < 8; ++j) xw[j] = xw[j + 4];
        // next 4 window floats (final iter's load lands in pad, value unused)
        const float4 xn = *(const float4*)&xs[SWZ(l0 + k + 12)];
        xw[8] = xn.x; xw[9] = xn.y; xw[10] = xn.z; xw[11] = xn.w;
    }

    // ---- combine 8 K-slice partials through LDS ----
    const int pbase = (ks << 9) + l0;
    *(float4*)&part[SWZ(pbase)]     = make_float4(acc[0], acc[1], acc[2], acc[3]);
    *(float4*)&part[SWZ(pbase + 4)] = make_float4(acc[4], acc[5], acc[6], acc[7]);
    __syncthreads();

    // ---- reduce + broadcast-store: thread tid owns output o = tid ----
    const int o = tid;             // 0..511
    float r = 0.0f;
    #pragma unroll
    for (int s = 0; s < 8; ++s)
        r += part[SWZ((s << 9) + o)];

    float* op = out + ((size_t)b << 18) + ((size_t)c << 10) + (half << 9) + o;
    #pragma unroll
    for (int rep = 0; rep < 16; ++rep) {
        *op = r;
        op += 1 << 14;   // next replica channel (+16*1024 floats)
    }
}

extern "C" void kernel_launch(void* const* d_in, const int* in_sizes, int n_in,
                              void* d_out, int out_size, void* d_ws, size_t ws_size,
                              hipStream_t stream)
{
    const float* x        = (const float*)d_in[0];
    const float* scales   = (const float*)d_in[1];
    const float* f_mod    = (const float*)d_in[2];
    const float* poly_mod = (const float*)d_in[3];
    const int*   i_ptr    = (const int*)d_in[4];
    float* out = (float*)d_out;

    wavconv_kernel<<<256, 512, 0, stream>>>(x, scales, f_mod, poly_mod, i_ptr, out);
}

// Round 4
// 10.456 us; speedup vs baseline: 2.0150x; 1.1721x over previous
//
#include <hip/hip_runtime.h>
#include <math.h>

// out[b, o, l] = sum_k x[b, o%16, l+k-511] * wav[o%16, k], B=8, C=S=16, L=1024.
// 256 output channels = 16 distinct rows, each broadcast 16x.
//
// Key insight (round 4): wav[k] = poly(u)*exp(-u/2), u=(k/sigma)^2, is one-sided
// and decays to <1e-15 of threshold once u >= ~100, i.e. k >= ~10*|sigma|.
// sigma = f_mod[i]*scale_c/(2*pi) is at most a few units, so the effective tap
// count kmax = 10*|sigma|+2 is ~3..60, not 1024. Compute only those taps
// (runtime bound, deterministic); the kernel becomes store-bound (8.39 MB out).
// Tail truncation error < 1e-11 absolute vs the 1.64 absolute threshold.

__global__ __launch_bounds__(256)
void wavconv_kernel(const float* __restrict__ x,
                    const float* __restrict__ scales,
                    const float* __restrict__ f_mod,
                    const float* __restrict__ poly_mod,
                    const int*   __restrict__ i_ptr,
                    float* __restrict__ out)
{
    __shared__ float xs[1536];   // zero-padded segment for this half (worst case 512+1024)
    __shared__ float wv[1024];   // wavelet taps [0, kmax)

    const int tid  = threadIdx.x;
    const int blk  = blockIdx.x;
    const int half = blk & 1;
    const int bc   = blk >> 1;     // b*16 + c
    const int c    = bc & 15;
    const int b    = bc >> 4;

    // ---- scalar params + runtime tap cutoff ----
    const int   ii = i_ptr[0];
    const float fm = f_mod[ii];
    const float p0 = poly_mod[ii * 3 + 0];
    const float p1 = poly_mod[ii * 3 + 1];
    const float p2 = poly_mod[ii * 3 + 2];
    const float sigma = fm * scales[c] * 0.15915494309189535f;  // fm*scale/(2*pi)
    // include all k with u = (k/sigma)^2 <= ~100  ->  k <= 10*|sigma|
    int kmax = (int)(fabsf(sigma) * 10.0f) + 2;
    if (kmax > 1024) kmax = 1024;

    // ---- wavelet taps k in [0, kmax) ----
    for (int k = tid; k < kmax; k += 256) {
        const float q  = (float)k / sigma;
        const float u  = q * q;
        const float u2 = u * u;
        const float poly = 1.0f - p0 * u + p1 * u2 + p2 * u2 * u;
        wv[k] = poly * expf(-0.5f * u);
    }

    // ---- stage zero-padded segment: xs[i] = xpad[half*512 + i], i in [0, 512+kmax) ----
    // xpad[m] = x[bc][m-511] (zero outside [511, 511+1024))
    const int nstage = 512 + kmax;
    const float* __restrict__ xrow = x + ((size_t)bc << 10);
    for (int i = tid; i < nstage; i += 256) {
        const int m = (half << 9) + i - 511;
        xs[i] = (m >= 0 && m < 1024) ? xrow[m] : 0.0f;
    }
    __syncthreads();

    // ---- correlation: thread owns outputs lo, lo+1 of this half ----
    const int lo = tid << 1;       // 0..510
    float a0 = 0.0f, a1 = 0.0f;
    #pragma unroll 4
    for (int k = 0; k < kmax; ++k) {
        const float w = wv[k];                 // wave-uniform broadcast
        a0 = fmaf(xs[lo + k],     w, a0);      // stride-2 lanes: 2-way alias, free
        a1 = fmaf(xs[lo + 1 + k], w, a1);
    }

    // ---- broadcast-store to the 16 replicated output channels ----
    const float2 res = make_float2(a0, a1);
    float* op = out + ((size_t)b << 18) + ((size_t)c << 10) + (half << 9) + lo;
    #pragma unroll
    for (int rep = 0; rep < 16; ++rep) {
        *(float2*)op = res;
        op += 1 << 14;   // next replica channel (+16*1024 floats)
    }
}

extern "C" void kernel_launch(void* const* d_in, const int* in_sizes, int n_in,
                              void* d_out, int out_size, void* d_ws, size_t ws_size,
                              hipStream_t stream)
{
    const float* x        = (const float*)d_in[0];
    const float* scales   = (const float*)d_in[1];
    const float* f_mod    = (const float*)d_in[2];
    const float* poly_mod = (const float*)d_in[3];
    const int*   i_ptr    = (const int*)d_in[4];
    float* out = (float*)d_out;

    wavconv_kernel<<<256, 256, 0, stream>>>(x, scales, f_mod, poly_mod, i_ptr, out);
}